// Round 1
// baseline (1180.973 us; speedup 1.0000x reference)
//
#include <hip/hip_runtime.h>

#define N_ROWS 65536
#define DIM    512
#define NSTEP  10

typedef float  f32x16 __attribute__((ext_vector_type(16)));
typedef float  f32x4  __attribute__((ext_vector_type(4)));
typedef short  s16x8  __attribute__((ext_vector_type(8)));
typedef unsigned int u32x2 __attribute__((ext_vector_type(2)));
typedef unsigned int u32x4 __attribute__((ext_vector_type(4)));

__device__ __forceinline__ unsigned f2bf(float f) {
  unsigned u = __float_as_uint(f);
  return (u + 0x7fffu + ((u >> 16) & 1u)) >> 16;  // RNE fp32 -> bf16
}
__device__ __forceinline__ unsigned pack2bf(float a, float b) {
  return f2bf(a) | (f2bf(b) << 16);
}
__device__ __forceinline__ float ftanh(float x) {
  float e = __expf(2.0f * x);
  return 1.0f - 2.0f / (e + 1.0f);
}
__device__ __forceinline__ float fsigm(float x) {
  return 1.0f / (1.0f + __expf(-x));
}
__device__ __forceinline__ void mfma(f32x16& c, s16x8 a, s16x8 b) {
  asm("v_mfma_f32_32x32x16_bf16 %0, %1, %2, %0" : "+v"(c) : "v"(a), "v"(b));
}

// Pack a 512x512 slice of a row-major fp32 weight matrix into bf16 MFMA A-frag
// order: frag (ks, otg) holds A[o=otg*32+(l&31)][k=ks*16+8*(l>>5)+i], i=0..7.
__global__ void pack_frags_kernel(const float* __restrict__ src, int row_stride,
                                  int col_off, unsigned short* __restrict__ dst) {
  const int idx = blockIdx.x * 256 + threadIdx.x;  // 0..32767
  const int l    = idx & 63;
  const int frag = idx >> 6;        // ks*16 + otg
  const int ks   = frag >> 4;
  const int otg  = frag & 15;
  const int o = otg * 32 + (l & 31);
  const int k = ks * 16 + (l >> 5) * 8;
  const float* p = src + (size_t)o * row_stride + col_off + k;
  s16x8 v;
#pragma unroll
  for (int i = 0; i < 8; ++i) v[i] = (short)f2bf(p[i]);
  *reinterpret_cast<s16x8*>(dst + (size_t)idx * 8) = v;
}

// c1[s][o] = b1[o] + t_s * W1[o][512]   (time-column folded into step bias)
__global__ void c1_kernel(const float* __restrict__ W1, const float* __restrict__ b1,
                          float* __restrict__ c1) {
  const int o = threadIdx.x;  // 512 threads
  const float wt = W1[(size_t)o * 513 + 512];
  const float bb = b1[o];
  for (int s = 0; s < NSTEP; ++s)
    c1[s * DIM + o] = bb + ((float)s * 0.1f) * wt;
}

__global__ __launch_bounds__(512, 2)
void ode_fused(const float* __restrict__ x, const float* __restrict__ h0,
               const float* __restrict__ b2, const float* __restrict__ bg,
               const unsigned short* __restrict__ w1f, const unsigned short* __restrict__ w2f,
               const unsigned short* __restrict__ wgaf, const unsigned short* __restrict__ wgbf,
               const float* __restrict__ c1, float* __restrict__ out)
{
  __shared__ char ldsA[64 * 1024];   // [64 m][512 k] bf16, XOR-swizzled
  __shared__ char ldsB[64 * 1024];

  const int tid = threadIdx.x;
  const int w   = tid >> 6;          // wave 0..7, owns o-rows [64w, 64w+64)
  const int l   = tid & 63;
  const int lm  = l & 31;
  const int h5  = l >> 5;
  const int m0  = blockIdx.x << 6;   // 64 rows per block
  const int ow  = w << 6;

  // ---------------- stage h0 -> ldsA (bf16, swizzled) ----------------
  {
    const int r  = tid >> 3;                    // 0..63
    const int c0 = (tid & 7) << 2;              // 0..28
    const float* src = h0 + (size_t)(m0 + r) * DIM;
    char* trow = ldsA + r * 1024;
    const unsigned sw = (r & 7) << 4;
#pragma unroll
    for (int j = 0; j < 16; ++j) {
      const int c = c0 + j * 32;
      f32x4 v = *reinterpret_cast<const f32x4*>(src + c);
      u32x2 pk;
      pk[0] = pack2bf(v[0], v[1]);
      pk[1] = pack2bf(v[2], v[3]);
      *reinterpret_cast<u32x2*>(trow + (((unsigned)(c << 1)) ^ sw)) = pk;
    }
  }

  // ---------------- fp32 h state in acc layout ----------------
  // value (ot,mt,reg=4g+j): m = m0+32*mt+lm (col), o = ow+32*ot+8g+4*h5+j (row)
  f32x16 hst[2][2];
#pragma unroll
  for (int ot = 0; ot < 2; ++ot)
#pragma unroll
    for (int mt = 0; mt < 2; ++mt) {
      const float* hr = h0 + (size_t)(m0 + (mt << 5) + lm) * DIM;
#pragma unroll
      for (int g = 0; g < 4; ++g) {
        const int oc = ow + (ot << 5) + (g << 3) + (h5 << 2);
        f32x4 v = *reinterpret_cast<const f32x4*>(hr + oc);
#pragma unroll
        for (int j = 0; j < 4; ++j) hst[ot][mt][(g << 2) + j] = v[j];
      }
    }

  const unsigned bm0 = (unsigned)lm << 10;
  const unsigned bm1 = (unsigned)(lm + 32) << 10;
  const unsigned sxm = (lm & 7) << 4;
  const unsigned kh  = (unsigned)h5 << 4;

  f32x16 acc[2][2];

  // P[o][m] += W[o][k] * tile[m][k] over K=512
  auto mm_lds = [&](const unsigned short* __restrict__ AF, const char* buf) {
    const s16x8* A = reinterpret_cast<const s16x8*>(AF);
#pragma unroll 4
    for (int ks = 0; ks < 32; ++ks) {
      const int fb = ((ks << 4) + (w << 1)) << 6;
      s16x8 a0 = A[fb + l];
      s16x8 a1 = A[fb + 64 + l];
      const unsigned ko = (((unsigned)ks << 5) + kh) ^ sxm;
      s16x8 b0 = *reinterpret_cast<const s16x8*>(buf + (bm0 + ko));
      s16x8 b1 = *reinterpret_cast<const s16x8*>(buf + (bm1 + ko));
      mfma(acc[0][0], a0, b0);
      mfma(acc[0][1], a0, b1);
      mfma(acc[1][0], a1, b0);
      mfma(acc[1][1], a1, b1);
    }
  };

  // broadcast per-o fp32 vector into acc
  auto acc_init = [&](const float* __restrict__ vec) {
#pragma unroll
    for (int ot = 0; ot < 2; ++ot)
#pragma unroll
      for (int g = 0; g < 4; ++g) {
        const int oc = ow + (ot << 5) + (g << 3) + (h5 << 2);
        f32x4 v = *reinterpret_cast<const f32x4*>(vec + oc);
#pragma unroll
        for (int mt = 0; mt < 2; ++mt)
#pragma unroll
          for (int j = 0; j < 4; ++j) acc[ot][mt][(g << 2) + j] = v[j];
      }
  };

  // write bf16(src) into tile[m][k=o] (wave's o-columns, all m rows)
  auto tile_write = [&](const f32x16 src[2][2], char* buf) {
#pragma unroll
    for (int mt = 0; mt < 2; ++mt) {
      const unsigned m = (unsigned)((mt << 5) + lm);
      char* trow = buf + (m << 10);
      const unsigned sw = (m & 7) << 4;
#pragma unroll
      for (int ot = 0; ot < 2; ++ot)
#pragma unroll
        for (int g = 0; g < 4; ++g) {
          const unsigned oc = (unsigned)(ow + (ot << 5) + (g << 3) + (h5 << 2));
          u32x2 pk;
          pk[0] = pack2bf(src[ot][mt][(g << 2) + 0], src[ot][mt][(g << 2) + 1]);
          pk[1] = pack2bf(src[ot][mt][(g << 2) + 2], src[ot][mt][(g << 2) + 3]);
          *reinterpret_cast<u32x2*>(trow + ((oc << 1) ^ sw)) = pk;
        }
    }
  };

  __syncthreads();  // staged tile visible

  for (int s = 0; s < NSTEP; ++s) {
    // H1 = tanh(W1 . Z^T + c1_s)
    acc_init(c1 + s * DIM);
    mm_lds(w1f, ldsA);
#pragma unroll
    for (int ot = 0; ot < 2; ++ot)
#pragma unroll
      for (int mt = 0; mt < 2; ++mt)
#pragma unroll
        for (int i = 0; i < 16; ++i) acc[ot][mt][i] = ftanh(acc[ot][mt][i]);
    tile_write(acc, ldsB);
    __syncthreads();
    // h += dt * tanh(W2 . H1^T + b2)
    acc_init(b2);
    mm_lds(w2f, ldsB);
#pragma unroll
    for (int ot = 0; ot < 2; ++ot)
#pragma unroll
      for (int mt = 0; mt < 2; ++mt)
#pragma unroll
        for (int i = 0; i < 16; ++i) hst[ot][mt][i] += 0.1f * ftanh(acc[ot][mt][i]);
    tile_write(hst, ldsA);
    __syncthreads();
  }

  // ---- gating: G = WgB . E^T + WgA . X^T + bg ----
  acc_init(bg);
  mm_lds(wgbf, ldsA);  // evolved part (tile holds E)
  {
    const s16x8* A = reinterpret_cast<const s16x8*>(wgaf);
    const float* xr0 = x + (size_t)(m0 + lm) * DIM;
    const float* xr1 = x + (size_t)(m0 + 32 + lm) * DIM;
#pragma unroll 2
    for (int ks = 0; ks < 32; ++ks) {
      const int fb = ((ks << 4) + (w << 1)) << 6;
      s16x8 a0 = A[fb + l];
      s16x8 a1 = A[fb + 64 + l];
      const int kc = (ks << 4) + (h5 << 3);
      f32x4 u0 = *reinterpret_cast<const f32x4*>(xr0 + kc);
      f32x4 u1 = *reinterpret_cast<const f32x4*>(xr0 + kc + 4);
      u32x4 pb;
      pb[0] = pack2bf(u0[0], u0[1]); pb[1] = pack2bf(u0[2], u0[3]);
      pb[2] = pack2bf(u1[0], u1[1]); pb[3] = pack2bf(u1[2], u1[3]);
      s16x8 b0 = __builtin_bit_cast(s16x8, pb);
      f32x4 w0 = *reinterpret_cast<const f32x4*>(xr1 + kc);
      f32x4 w1 = *reinterpret_cast<const f32x4*>(xr1 + kc + 4);
      u32x4 qb;
      qb[0] = pack2bf(w0[0], w0[1]); qb[1] = pack2bf(w0[2], w0[3]);
      qb[2] = pack2bf(w1[0], w1[1]); qb[3] = pack2bf(w1[2], w1[3]);
      s16x8 b1 = __builtin_bit_cast(s16x8, qb);
      mfma(acc[0][0], a0, b0);
      mfma(acc[0][1], a0, b1);
      mfma(acc[1][0], a1, b0);
      mfma(acc[1][1], a1, b1);
    }
  }

  // ---- blend + store both output copies ----
  float* out1 = out + (size_t)N_ROWS * DIM;
#pragma unroll
  for (int mt = 0; mt < 2; ++mt) {
    const int m = m0 + (mt << 5) + lm;
    const float* xr = x + (size_t)m * DIM;
    float* o0p = out  + (size_t)m * DIM;
    float* o1p = out1 + (size_t)m * DIM;
#pragma unroll
    for (int ot = 0; ot < 2; ++ot)
#pragma unroll
      for (int g = 0; g < 4; ++g) {
        const int oc = ow + (ot << 5) + (g << 3) + (h5 << 2);
        f32x4 xv = *reinterpret_cast<const f32x4*>(xr + oc);
        f32x4 r;
#pragma unroll
        for (int j = 0; j < 4; ++j) {
          const float gt = fsigm(acc[ot][mt][(g << 2) + j]);
          const float ev = hst[ot][mt][(g << 2) + j];
          r[j] = gt * ev + (1.0f - gt) * xv[j];
        }
        *reinterpret_cast<f32x4*>(o0p + oc) = r;
        *reinterpret_cast<f32x4*>(o1p + oc) = r;
      }
  }
}

extern "C" void kernel_launch(void* const* d_in, const int* in_sizes, int n_in,
                              void* d_out, int out_size, void* d_ws, size_t ws_size,
                              hipStream_t stream) {
  const float* x  = (const float*)d_in[0];
  const float* h0 = (const float*)d_in[1];
  const float* W1 = (const float*)d_in[2];
  const float* b1 = (const float*)d_in[3];
  const float* W2 = (const float*)d_in[4];
  const float* b2 = (const float*)d_in[5];
  const float* Wg = (const float*)d_in[6];
  const float* bg = (const float*)d_in[7];

  char* ws = (char*)d_ws;
  const size_t FRAG_BYTES = (size_t)512 * 512 * 2;  // 512 KB each
  unsigned short* w1f  = (unsigned short*)(ws + 0 * FRAG_BYTES);
  unsigned short* w2f  = (unsigned short*)(ws + 1 * FRAG_BYTES);
  unsigned short* wgaf = (unsigned short*)(ws + 2 * FRAG_BYTES);
  unsigned short* wgbf = (unsigned short*)(ws + 3 * FRAG_BYTES);
  float*          c1   = (float*)(ws + 4 * FRAG_BYTES);

  pack_frags_kernel<<<128, 256, 0, stream>>>(W1, 513, 0,   w1f);
  pack_frags_kernel<<<128, 256, 0, stream>>>(W2, 512, 0,   w2f);
  pack_frags_kernel<<<128, 256, 0, stream>>>(Wg, 1024, 0,  wgaf);
  pack_frags_kernel<<<128, 256, 0, stream>>>(Wg, 1024, 512, wgbf);
  c1_kernel<<<1, 512, 0, stream>>>(W1, b1, c1);

  ode_fused<<<N_ROWS / 64, 512, 0, stream>>>(x, h0, b2, bg, w1f, w2f, wgaf, wgbf,
                                             c1, (float*)d_out);
}

// Round 4
// 984.438 us; speedup vs baseline: 1.1996x; 1.1996x over previous
//
#include <hip/hip_runtime.h>

#define N_ROWS 65536
#define DIM    512
#define NSTEP  10

typedef float  f32x16 __attribute__((ext_vector_type(16)));
typedef float  f32x4  __attribute__((ext_vector_type(4)));
typedef short  s16x8  __attribute__((ext_vector_type(8)));
typedef unsigned int u32x2 __attribute__((ext_vector_type(2)));
typedef unsigned int u32x4 __attribute__((ext_vector_type(4)));

__device__ __forceinline__ unsigned f2bf(float f) {
  unsigned u = __float_as_uint(f);
  return (u + 0x7fffu + ((u >> 16) & 1u)) >> 16;  // exact RNE fp32 -> bf16
}
// nearest rounding (ties away from zero), packed: 5 ops/pair, no coherent bias
__device__ __forceinline__ unsigned pack2bf_rn(float a, float b) {
  unsigned ua = __float_as_uint(a) + 0x8000u;
  unsigned ub = __float_as_uint(b) + 0x8000u;
  return (ua >> 16) | (ub & 0xffff0000u);
}
#define LOG2E_X2 2.885390081777927f
#define LOG2E    1.442695040888963f
__device__ __forceinline__ float ftanh(float x) {   // 1 - 2/(1+2^(2x*log2e))
  float t = __builtin_amdgcn_exp2f(x * LOG2E_X2);
  float r = __builtin_amdgcn_rcpf(1.0f + t);
  return __builtin_fmaf(-2.0f, r, 1.0f);
}
__device__ __forceinline__ float fsigm(float x) {
  float t = __builtin_amdgcn_exp2f(-x * LOG2E);
  return __builtin_amdgcn_rcpf(1.0f + t);
}
__device__ __forceinline__ void mfma(f32x16& c, s16x8 a, s16x8 b) {
  asm("v_mfma_f32_32x32x16_bf16 %0, %1, %2, %0" : "+v"(c) : "v"(a), "v"(b));
}

// Pack a 512x512 slice of a row-major fp32 weight matrix into bf16 MFMA A-frag
// order (R1-proven): frag (ks, otg) holds A[o=otg*32+(l&31)][k=ks*16+8*(l>>5)+i].
__global__ void pack_frags_kernel(const float* __restrict__ src, int row_stride,
                                  int col_off, unsigned short* __restrict__ dst) {
  const int idx = blockIdx.x * 256 + threadIdx.x;  // 0..32767
  const int l    = idx & 63;
  const int frag = idx >> 6;        // ks*16 + otg
  const int ks   = frag >> 4;
  const int otg  = frag & 15;
  const int o = otg * 32 + (l & 31);
  const int k = ks * 16 + (l >> 5) * 8;
  const float* p = src + (size_t)o * row_stride + col_off + k;
  s16x8 v;
#pragma unroll
  for (int i = 0; i < 8; ++i) v[i] = (short)f2bf(p[i]);
  *reinterpret_cast<s16x8*>(dst + (size_t)idx * 8) = v;
}

// c1[s][o] = b1[o] + t_s * W1[o][512]   (time-column folded into step bias)
__global__ void c1_kernel(const float* __restrict__ W1, const float* __restrict__ b1,
                          float* __restrict__ c1) {
  const int o = threadIdx.x;  // 512 threads
  const float wt = W1[(size_t)o * 513 + 512];
  const float bb = b1[o];
  for (int s = 0; s < NSTEP; ++s)
    c1[s * DIM + o] = bb + ((float)s * 0.1f) * wt;
}

__global__ __launch_bounds__(512, 2)
void ode_fused(const float* __restrict__ x, const float* __restrict__ h0,
               const float* __restrict__ b2, const float* __restrict__ bg,
               const unsigned short* __restrict__ w1f, const unsigned short* __restrict__ w2f,
               const unsigned short* __restrict__ wgaf, const unsigned short* __restrict__ wgbf,
               const float* __restrict__ c1, float* __restrict__ out)
{
  __shared__ char ldsA[64 * 1024];   // [64 m][512 k] bf16, XOR-swizzled
  __shared__ char ldsB[64 * 1024];

  const int tid = threadIdx.x;
  const int w   = tid >> 6;          // wave 0..7, owns o-rows [64w, 64w+64)
  const int l   = tid & 63;
  const int lm  = l & 31;
  const int h5  = l >> 5;
  const int m0  = blockIdx.x << 6;   // 64 rows per block
  const int ow  = w << 6;

  // ---------------- stage h0 -> ldsA (bf16, swizzled) ----------------
  {
    const int r  = tid >> 3;                    // 0..63
    const int c0 = (tid & 7) << 2;              // 0..28
    const float* src = h0 + (size_t)(m0 + r) * DIM;
    char* trow = ldsA + r * 1024;
    const unsigned sw = (r & 7) << 4;
#pragma unroll
    for (int j = 0; j < 16; ++j) {
      const int c = c0 + j * 32;
      f32x4 v = *reinterpret_cast<const f32x4*>(src + c);
      u32x2 pk;
      pk[0] = pack2bf_rn(v[0], v[1]);
      pk[1] = pack2bf_rn(v[2], v[3]);
      *reinterpret_cast<u32x2*>(trow + (((unsigned)(c << 1)) ^ sw)) = pk;
    }
  }

  // ---------------- fp32 h state in acc layout ----------------
  // value (ot,mt,reg=4g+j): m = m0+32*mt+lm (col), o = ow+32*ot+8g+4*h5+j (row)
  f32x16 hst[2][2];
#pragma unroll
  for (int ot = 0; ot < 2; ++ot)
#pragma unroll
    for (int mt = 0; mt < 2; ++mt) {
      const float* hr = h0 + (size_t)(m0 + (mt << 5) + lm) * DIM;
#pragma unroll
      for (int g = 0; g < 4; ++g) {
        const int oc = ow + (ot << 5) + (g << 3) + (h5 << 2);
        f32x4 v = *reinterpret_cast<const f32x4*>(hr + oc);
#pragma unroll
        for (int j = 0; j < 4; ++j) hst[ot][mt][(g << 2) + j] = v[j];
      }
    }

  const unsigned bm0 = (unsigned)lm << 10;
  const unsigned bm1 = (unsigned)(lm + 32) << 10;
  const unsigned sxm = (lm & 7) << 4;
  const unsigned kh  = (unsigned)h5 << 4;

  f32x16 acc[2][2];

  // P[o][m] += W[o][k] * tile[m][k] over K=512  (R1-proven rolled form)
  auto mm_lds = [&](const unsigned short* __restrict__ AF, const char* buf) {
    const s16x8* A = reinterpret_cast<const s16x8*>(AF);
#pragma unroll 4
    for (int ks = 0; ks < 32; ++ks) {
      const int fb = ((ks << 4) + (w << 1)) << 6;
      s16x8 a0 = A[fb + l];
      s16x8 a1 = A[fb + 64 + l];
      const unsigned ko = (((unsigned)ks << 5) + kh) ^ sxm;
      s16x8 b0 = *reinterpret_cast<const s16x8*>(buf + (bm0 + ko));
      s16x8 b1 = *reinterpret_cast<const s16x8*>(buf + (bm1 + ko));
      mfma(acc[0][0], a0, b0);
      mfma(acc[0][1], a0, b1);
      mfma(acc[1][0], a1, b0);
      mfma(acc[1][1], a1, b1);
    }
  };

  // broadcast per-o fp32 vector into acc
  auto acc_init = [&](const float* __restrict__ vec) {
#pragma unroll
    for (int ot = 0; ot < 2; ++ot)
#pragma unroll
      for (int g = 0; g < 4; ++g) {
        const int oc = ow + (ot << 5) + (g << 3) + (h5 << 2);
        f32x4 v = *reinterpret_cast<const f32x4*>(vec + oc);
#pragma unroll
        for (int mt = 0; mt < 2; ++mt)
#pragma unroll
          for (int j = 0; j < 4; ++j) acc[ot][mt][(g << 2) + j] = v[j];
      }
  };

  // write bf16(src) into tile[m][k=o] (wave's o-columns, all m rows)
  auto tile_write = [&](const f32x16 src[2][2], char* buf) {
#pragma unroll
    for (int mt = 0; mt < 2; ++mt) {
      const unsigned m = (unsigned)((mt << 5) + lm);
      char* trow = buf + (m << 10);
      const unsigned sw = (m & 7) << 4;
#pragma unroll
      for (int ot = 0; ot < 2; ++ot)
#pragma unroll
        for (int g = 0; g < 4; ++g) {
          const unsigned oc = (unsigned)(ow + (ot << 5) + (g << 3) + (h5 << 2));
          u32x2 pk;
          pk[0] = pack2bf_rn(src[ot][mt][(g << 2) + 0], src[ot][mt][(g << 2) + 1]);
          pk[1] = pack2bf_rn(src[ot][mt][(g << 2) + 2], src[ot][mt][(g << 2) + 3]);
          *reinterpret_cast<u32x2*>(trow + ((oc << 1) ^ sw)) = pk;
        }
    }
  };

  __syncthreads();  // staged tile visible

  for (int s = 0; s < NSTEP; ++s) {
    // H1 = tanh(W1 . Z^T + c1_s)
    acc_init(c1 + s * DIM);
    mm_lds(w1f, ldsA);
#pragma unroll
    for (int ot = 0; ot < 2; ++ot)
#pragma unroll
      for (int mt = 0; mt < 2; ++mt)
#pragma unroll
        for (int i = 0; i < 16; ++i) acc[ot][mt][i] = ftanh(acc[ot][mt][i]);
    tile_write(acc, ldsB);
    __syncthreads();
    // h += dt * tanh(W2 . H1^T + b2)  == fma(-0.2, rcp(1+e^{2a}), h+0.1)
    acc_init(b2);
    mm_lds(w2f, ldsB);
#pragma unroll
    for (int ot = 0; ot < 2; ++ot)
#pragma unroll
      for (int mt = 0; mt < 2; ++mt)
#pragma unroll
        for (int i = 0; i < 16; ++i) {
          float t = __builtin_amdgcn_exp2f(acc[ot][mt][i] * LOG2E_X2);
          float r = __builtin_amdgcn_rcpf(1.0f + t);
          hst[ot][mt][i] = __builtin_fmaf(-0.2f, r, hst[ot][mt][i] + 0.1f);
        }
    tile_write(hst, ldsA);
    __syncthreads();
  }

  // ---- gating: G = WgB . E^T + WgA . X^T + bg ----
  acc_init(bg);
  mm_lds(wgbf, ldsA);  // evolved part (tile holds E)
  {
    const s16x8* A = reinterpret_cast<const s16x8*>(wgaf);
    const float* xr0 = x + (size_t)(m0 + lm) * DIM;
    const float* xr1 = x + (size_t)(m0 + 32 + lm) * DIM;
#pragma unroll 2
    for (int ks = 0; ks < 32; ++ks) {
      const int fb = ((ks << 4) + (w << 1)) << 6;
      s16x8 a0 = A[fb + l];
      s16x8 a1 = A[fb + 64 + l];
      const int kc = (ks << 4) + (h5 << 3);
      f32x4 u0 = *reinterpret_cast<const f32x4*>(xr0 + kc);
      f32x4 u1 = *reinterpret_cast<const f32x4*>(xr0 + kc + 4);
      u32x4 pb;
      pb[0] = pack2bf_rn(u0[0], u0[1]); pb[1] = pack2bf_rn(u0[2], u0[3]);
      pb[2] = pack2bf_rn(u1[0], u1[1]); pb[3] = pack2bf_rn(u1[2], u1[3]);
      s16x8 b0 = __builtin_bit_cast(s16x8, pb);
      f32x4 w0 = *reinterpret_cast<const f32x4*>(xr1 + kc);
      f32x4 w1 = *reinterpret_cast<const f32x4*>(xr1 + kc + 4);
      u32x4 qb;
      qb[0] = pack2bf_rn(w0[0], w0[1]); qb[1] = pack2bf_rn(w0[2], w0[3]);
      qb[2] = pack2bf_rn(w1[0], w1[1]); qb[3] = pack2bf_rn(w1[2], w1[3]);
      s16x8 b1 = __builtin_bit_cast(s16x8, qb);
      mfma(acc[0][0], a0, b0);
      mfma(acc[0][1], a0, b1);
      mfma(acc[1][0], a1, b0);
      mfma(acc[1][1], a1, b1);
    }
  }

  // ---- blend + store both output copies ----
  float* out1 = out + (size_t)N_ROWS * DIM;
#pragma unroll
  for (int mt = 0; mt < 2; ++mt) {
    const int m = m0 + (mt << 5) + lm;
    const float* xr = x + (size_t)m * DIM;
    float* o0p = out  + (size_t)m * DIM;
    float* o1p = out1 + (size_t)m * DIM;
#pragma unroll
    for (int ot = 0; ot < 2; ++ot)
#pragma unroll
      for (int g = 0; g < 4; ++g) {
        const int oc = ow + (ot << 5) + (g << 3) + (h5 << 2);
        f32x4 xv = *reinterpret_cast<const f32x4*>(xr + oc);
        f32x4 r;
#pragma unroll
        for (int j = 0; j < 4; ++j) {
          const float gt = fsigm(acc[ot][mt][(g << 2) + j]);
          const float ev = hst[ot][mt][(g << 2) + j];
          r[j] = gt * ev + (1.0f - gt) * xv[j];
        }
        *reinterpret_cast<f32x4*>(o0p + oc) = r;
        *reinterpret_cast<f32x4*>(o1p + oc) = r;
      }
  }
}

extern "C" void kernel_launch(void* const* d_in, const int* in_sizes, int n_in,
                              void* d_out, int out_size, void* d_ws, size_t ws_size,
                              hipStream_t stream) {
  const float* x  = (const float*)d_in[0];
  const float* h0 = (const float*)d_in[1];
  const float* W1 = (const float*)d_in[2];
  const float* b1 = (const float*)d_in[3];
  const float* W2 = (const float*)d_in[4];
  const float* b2 = (const float*)d_in[5];
  const float* Wg = (const float*)d_in[6];
  const float* bg = (const float*)d_in[7];

  char* ws = (char*)d_ws;
  const size_t FRAG_BYTES = (size_t)512 * 512 * 2;  // 512 KB each
  unsigned short* w1f  = (unsigned short*)(ws + 0 * FRAG_BYTES);
  unsigned short* w2f  = (unsigned short*)(ws + 1 * FRAG_BYTES);
  unsigned short* wgaf = (unsigned short*)(ws + 2 * FRAG_BYTES);
  unsigned short* wgbf = (unsigned short*)(ws + 3 * FRAG_BYTES);
  float*          c1   = (float*)(ws + 4 * FRAG_BYTES);

  pack_frags_kernel<<<128, 256, 0, stream>>>(W1, 513, 0,   w1f);
  pack_frags_kernel<<<128, 256, 0, stream>>>(W2, 512, 0,   w2f);
  pack_frags_kernel<<<128, 256, 0, stream>>>(Wg, 1024, 0,  wgaf);
  pack_frags_kernel<<<128, 256, 0, stream>>>(Wg, 1024, 512, wgbf);
  c1_kernel<<<1, 512, 0, stream>>>(W1, b1, c1);

  ode_fused<<<N_ROWS / 64, 512, 0, stream>>>(x, h0, b2, bg, w1f, w2f, wgaf, wgbf,
                                             c1, (float*)d_out);
}

// Round 5
// 957.213 us; speedup vs baseline: 1.2338x; 1.0284x over previous
//
#include <hip/hip_runtime.h>

#define N_ROWS 65536
#define DIM    512
#define NSTEP  10

typedef float  f32x16 __attribute__((ext_vector_type(16)));
typedef float  f32x4  __attribute__((ext_vector_type(4)));
typedef short  s16x8  __attribute__((ext_vector_type(8)));
typedef __bf16 bf16x8 __attribute__((ext_vector_type(8)));
typedef unsigned int u32x2 __attribute__((ext_vector_type(2)));
typedef unsigned int u32x4 __attribute__((ext_vector_type(4)));

__device__ __forceinline__ unsigned f2bf(float f) {
  unsigned u = __float_as_uint(f);
  return (u + 0x7fffu + ((u >> 16) & 1u)) >> 16;  // exact RNE fp32 -> bf16
}
// nearest rounding (ties away from zero), packed via v_perm: bit-identical to
// ((bits(a)+0x8000)>>16) | ((bits(b)+0x8000)&0xffff0000)
__device__ __forceinline__ unsigned pack2bf_rn(float a, float b) {
  unsigned ua = __float_as_uint(a) + 0x8000u;
  unsigned ub = __float_as_uint(b) + 0x8000u;
  return __builtin_amdgcn_perm(ub, ua, 0x07060302u);
}
#define LOG2E_X2 2.885390081777927f
#define LOG2E    1.442695040888963f
__device__ __forceinline__ float ftanh(float x) {   // 1 - 2/(1+2^(2x*log2e))
  float t = __builtin_amdgcn_exp2f(x * LOG2E_X2);
  float r = __builtin_amdgcn_rcpf(1.0f + t);
  return __builtin_fmaf(-2.0f, r, 1.0f);
}
__device__ __forceinline__ float fsigm(float x) {
  float t = __builtin_amdgcn_exp2f(-x * LOG2E);
  return __builtin_amdgcn_rcpf(1.0f + t);
}
__device__ __forceinline__ void mfma(f32x16& c, s16x8 a, s16x8 b) {
  c = __builtin_amdgcn_mfma_f32_32x32x16_bf16(
        __builtin_bit_cast(bf16x8, a), __builtin_bit_cast(bf16x8, b), c, 0, 0, 0);
}

// Pack a 512x512 slice of a row-major fp32 weight matrix into bf16 MFMA A-frag
// order (R1-proven): frag (ks, otg) holds A[o=otg*32+(l&31)][k=ks*16+8*(l>>5)+i].
__global__ void pack_frags_kernel(const float* __restrict__ src, int row_stride,
                                  int col_off, unsigned short* __restrict__ dst) {
  const int idx = blockIdx.x * 256 + threadIdx.x;  // 0..32767
  const int l    = idx & 63;
  const int frag = idx >> 6;        // ks*16 + otg
  const int ks   = frag >> 4;
  const int otg  = frag & 15;
  const int o = otg * 32 + (l & 31);
  const int k = ks * 16 + (l >> 5) * 8;
  const float* p = src + (size_t)o * row_stride + col_off + k;
  s16x8 v;
#pragma unroll
  for (int i = 0; i < 8; ++i) v[i] = (short)f2bf(p[i]);
  *reinterpret_cast<s16x8*>(dst + (size_t)idx * 8) = v;
}

// c1[s][o] = b1[o] + t_s * W1[o][512]   (time-column folded into step bias)
__global__ void c1_kernel(const float* __restrict__ W1, const float* __restrict__ b1,
                          float* __restrict__ c1) {
  const int o = threadIdx.x;  // 512 threads
  const float wt = W1[(size_t)o * 513 + 512];
  const float bb = b1[o];
  for (int s = 0; s < NSTEP; ++s)
    c1[s * DIM + o] = bb + ((float)s * 0.1f) * wt;
}

__global__ __launch_bounds__(512, 2)
void ode_fused(const float* __restrict__ x, const float* __restrict__ h0,
               const float* __restrict__ b2, const float* __restrict__ bg,
               const unsigned short* __restrict__ w1f, const unsigned short* __restrict__ w2f,
               const unsigned short* __restrict__ wgaf, const unsigned short* __restrict__ wgbf,
               const float* __restrict__ c1, float* __restrict__ out)
{
  __shared__ char ldsA[64 * 1024];   // [64 m][512 k] bf16, XOR-swizzled
  __shared__ char ldsB[64 * 1024];

  const int tid = threadIdx.x;
  const int w   = tid >> 6;          // wave 0..7, owns o-rows [64w, 64w+64)
  const int l   = tid & 63;
  const int lm  = l & 31;
  const int h5  = l >> 5;
  const int m0  = blockIdx.x << 6;   // 64 rows per block
  const int ow  = w << 6;
  const int rot = blockIdx.x & 31;   // per-block K-phase rotation (L2 de-hotspot)

  // ---------------- stage h0 -> ldsA (bf16, swizzled) ----------------
  {
    const int r  = tid >> 3;                    // 0..63
    const int c0 = (tid & 7) << 2;              // 0..28
    const float* src = h0 + (size_t)(m0 + r) * DIM;
    char* trow = ldsA + r * 1024;
    const unsigned sw = (r & 7) << 4;
#pragma unroll
    for (int j = 0; j < 16; ++j) {
      const int c = c0 + j * 32;
      f32x4 v = *reinterpret_cast<const f32x4*>(src + c);
      u32x2 pk;
      pk[0] = pack2bf_rn(v[0], v[1]);
      pk[1] = pack2bf_rn(v[2], v[3]);
      *reinterpret_cast<u32x2*>(trow + (((unsigned)(c << 1)) ^ sw)) = pk;
    }
  }

  // ---------------- fp32 h state in acc layout ----------------
  // value (ot,mt,reg=4g+j): m = m0+32*mt+lm (col), o = ow+32*ot+8g+4*h5+j (row)
  f32x16 hst[2][2];
#pragma unroll
  for (int ot = 0; ot < 2; ++ot)
#pragma unroll
    for (int mt = 0; mt < 2; ++mt) {
      const float* hr = h0 + (size_t)(m0 + (mt << 5) + lm) * DIM;
#pragma unroll
      for (int g = 0; g < 4; ++g) {
        const int oc = ow + (ot << 5) + (g << 3) + (h5 << 2);
        f32x4 v = *reinterpret_cast<const f32x4*>(hr + oc);
#pragma unroll
        for (int j = 0; j < 4; ++j) hst[ot][mt][(g << 2) + j] = v[j];
      }
    }

  const unsigned bm0 = (unsigned)lm << 10;
  const unsigned bm1 = (unsigned)(lm + 32) << 10;
  const unsigned sxm = (lm & 7) << 4;
  const unsigned kh  = (unsigned)h5 << 4;

  f32x16 acc[2][2];

  // P[o][m] += W[o][k] * tile[m][k] over K=512, k-window rotated per block
  auto mm_lds = [&](const unsigned short* __restrict__ AF, const char* buf) {
    const s16x8* A = reinterpret_cast<const s16x8*>(AF);
#pragma unroll 4
    for (int ks = 0; ks < 32; ++ks) {
      const int kk = (ks + rot) & 31;
      const int fb = ((kk << 4) + (w << 1)) << 6;
      s16x8 a0 = A[fb + l];
      s16x8 a1 = A[fb + 64 + l];
      const unsigned ko = (((unsigned)kk << 5) + kh) ^ sxm;
      s16x8 b0 = *reinterpret_cast<const s16x8*>(buf + (bm0 + ko));
      s16x8 b1 = *reinterpret_cast<const s16x8*>(buf + (bm1 + ko));
      mfma(acc[0][0], a0, b0);
      mfma(acc[0][1], a0, b1);
      mfma(acc[1][0], a1, b0);
      mfma(acc[1][1], a1, b1);
    }
  };

  // broadcast per-o fp32 vector into acc
  auto acc_init = [&](const float* __restrict__ vec) {
#pragma unroll
    for (int ot = 0; ot < 2; ++ot)
#pragma unroll
      for (int g = 0; g < 4; ++g) {
        const int oc = ow + (ot << 5) + (g << 3) + (h5 << 2);
        f32x4 v = *reinterpret_cast<const f32x4*>(vec + oc);
#pragma unroll
        for (int mt = 0; mt < 2; ++mt)
#pragma unroll
          for (int j = 0; j < 4; ++j) acc[ot][mt][(g << 2) + j] = v[j];
      }
  };

  // write bf16(src) into tile[m][k=o] (wave's o-columns, all m rows)
  auto tile_write = [&](const f32x16 src[2][2], char* buf) {
#pragma unroll
    for (int mt = 0; mt < 2; ++mt) {
      const unsigned m = (unsigned)((mt << 5) + lm);
      char* trow = buf + (m << 10);
      const unsigned sw = (m & 7) << 4;
#pragma unroll
      for (int ot = 0; ot < 2; ++ot)
#pragma unroll
        for (int g = 0; g < 4; ++g) {
          const unsigned oc = (unsigned)(ow + (ot << 5) + (g << 3) + (h5 << 2));
          u32x2 pk;
          pk[0] = pack2bf_rn(src[ot][mt][(g << 2) + 0], src[ot][mt][(g << 2) + 1]);
          pk[1] = pack2bf_rn(src[ot][mt][(g << 2) + 2], src[ot][mt][(g << 2) + 3]);
          *reinterpret_cast<u32x2*>(trow + ((oc << 1) ^ sw)) = pk;
        }
    }
  };

  __syncthreads();  // staged tile visible

  for (int s = 0; s < NSTEP; ++s) {
    // H1 = tanh(W1 . Z^T + c1_s)
    acc_init(c1 + s * DIM);
    mm_lds(w1f, ldsA);
#pragma unroll
    for (int ot = 0; ot < 2; ++ot)
#pragma unroll
      for (int mt = 0; mt < 2; ++mt)
#pragma unroll
        for (int i = 0; i < 16; ++i) acc[ot][mt][i] = ftanh(acc[ot][mt][i]);
    tile_write(acc, ldsB);
    __syncthreads();
    // h += dt * tanh(W2 . H1^T + b2)  == fma(-0.2, rcp(1+e^{2a}), h+0.1)
    acc_init(b2);
    mm_lds(w2f, ldsB);
#pragma unroll
    for (int ot = 0; ot < 2; ++ot)
#pragma unroll
      for (int mt = 0; mt < 2; ++mt)
#pragma unroll
        for (int i = 0; i < 16; ++i) {
          float t = __builtin_amdgcn_exp2f(acc[ot][mt][i] * LOG2E_X2);
          float r = __builtin_amdgcn_rcpf(1.0f + t);
          hst[ot][mt][i] = __builtin_fmaf(-0.2f, r, hst[ot][mt][i] + 0.1f);
        }
    tile_write(hst, ldsA);
    __syncthreads();
  }

  // ---- gating: G = WgB . E^T + WgA . X^T + bg ----
  acc_init(bg);
  mm_lds(wgbf, ldsA);  // evolved part (tile holds E)
  {
    const s16x8* A = reinterpret_cast<const s16x8*>(wgaf);
    const float* xr0 = x + (size_t)(m0 + lm) * DIM;
    const float* xr1 = x + (size_t)(m0 + 32 + lm) * DIM;
#pragma unroll 2
    for (int ks = 0; ks < 32; ++ks) {
      const int kk = (ks + rot) & 31;
      const int fb = ((kk << 4) + (w << 1)) << 6;
      s16x8 a0 = A[fb + l];
      s16x8 a1 = A[fb + 64 + l];
      const int kc = (kk << 4) + (h5 << 3);
      f32x4 u0 = *reinterpret_cast<const f32x4*>(xr0 + kc);
      f32x4 u1 = *reinterpret_cast<const f32x4*>(xr0 + kc + 4);
      u32x4 pb;
      pb[0] = pack2bf_rn(u0[0], u0[1]); pb[1] = pack2bf_rn(u0[2], u0[3]);
      pb[2] = pack2bf_rn(u1[0], u1[1]); pb[3] = pack2bf_rn(u1[2], u1[3]);
      s16x8 b0 = __builtin_bit_cast(s16x8, pb);
      f32x4 w0 = *reinterpret_cast<const f32x4*>(xr1 + kc);
      f32x4 w1 = *reinterpret_cast<const f32x4*>(xr1 + kc + 4);
      u32x4 qb;
      qb[0] = pack2bf_rn(w0[0], w0[1]); qb[1] = pack2bf_rn(w0[2], w0[3]);
      qb[2] = pack2bf_rn(w1[0], w1[1]); qb[3] = pack2bf_rn(w1[2], w1[3]);
      s16x8 b1 = __builtin_bit_cast(s16x8, qb);
      mfma(acc[0][0], a0, b0);
      mfma(acc[0][1], a0, b1);
      mfma(acc[1][0], a1, b0);
      mfma(acc[1][1], a1, b1);
    }
  }

  // ---- blend + store both output copies ----
  float* out1 = out + (size_t)N_ROWS * DIM;
#pragma unroll
  for (int mt = 0; mt < 2; ++mt) {
    const int m = m0 + (mt << 5) + lm;
    const float* xr = x + (size_t)m * DIM;
    float* o0p = out  + (size_t)m * DIM;
    float* o1p = out1 + (size_t)m * DIM;
#pragma unroll
    for (int ot = 0; ot < 2; ++ot)
#pragma unroll
      for (int g = 0; g < 4; ++g) {
        const int oc = ow + (ot << 5) + (g << 3) + (h5 << 2);
        f32x4 xv = *reinterpret_cast<const f32x4*>(xr + oc);
        f32x4 r;
#pragma unroll
        for (int j = 0; j < 4; ++j) {
          const float gt = fsigm(acc[ot][mt][(g << 2) + j]);
          const float ev = hst[ot][mt][(g << 2) + j];
          r[j] = gt * ev + (1.0f - gt) * xv[j];
        }
        *reinterpret_cast<f32x4*>(o0p + oc) = r;
        *reinterpret_cast<f32x4*>(o1p + oc) = r;
      }
  }
}

extern "C" void kernel_launch(void* const* d_in, const int* in_sizes, int n_in,
                              void* d_out, int out_size, void* d_ws, size_t ws_size,
                              hipStream_t stream) {
  const float* x  = (const float*)d_in[0];
  const float* h0 = (const float*)d_in[1];
  const float* W1 = (const float*)d_in[2];
  const float* b1 = (const float*)d_in[3];
  const float* W2 = (const float*)d_in[4];
  const float* b2 = (const float*)d_in[5];
  const float* Wg = (const float*)d_in[6];
  const float* bg = (const float*)d_in[7];

  char* ws = (char*)d_ws;
  const size_t FRAG_BYTES = (size_t)512 * 512 * 2;  // 512 KB each
  unsigned short* w1f  = (unsigned short*)(ws + 0 * FRAG_BYTES);
  unsigned short* w2f  = (unsigned short*)(ws + 1 * FRAG_BYTES);
  unsigned short* wgaf = (unsigned short*)(ws + 2 * FRAG_BYTES);
  unsigned short* wgbf = (unsigned short*)(ws + 3 * FRAG_BYTES);
  float*          c1   = (float*)(ws + 4 * FRAG_BYTES);

  pack_frags_kernel<<<128, 256, 0, stream>>>(W1, 513, 0,   w1f);
  pack_frags_kernel<<<128, 256, 0, stream>>>(W2, 512, 0,   w2f);
  pack_frags_kernel<<<128, 256, 0, stream>>>(Wg, 1024, 0,  wgaf);
  pack_frags_kernel<<<128, 256, 0, stream>>>(Wg, 1024, 512, wgbf);
  c1_kernel<<<1, 512, 0, stream>>>(W1, b1, c1);

  ode_fused<<<N_ROWS / 64, 512, 0, stream>>>(x, h0, b2, bg, w1f, w2f, wgaf, wgbf,
                                             c1, (float*)d_out);
}